// Round 3
// baseline (365.026 us; speedup 1.0000x reference)
//
#include <hip/hip_runtime.h>
#include <math.h>

#define TOKENS 8192
#define DIM 4096
#define NEXP 256
#define TK 8
#define ROUTE_SCALE 2.5f
#define TH1 1e-5f   // score-gap trust threshold (~20x worst-case f16-split score error)
#define TH2 2e-5f   // group-score (sum of 2) gap threshold

#define PITCH 40    // halves per LDS row: 80 B = 5*16 -> b128-aligned every row, odd stride banks

typedef _Float16 half8 __attribute__((ext_vector_type(8)));
typedef float f4 __attribute__((ext_vector_type(4)));
union H8 { half8 v; int4 q; };

// ---------------------------------------------------------------------------
// Pre-kernel: pack W*256 into MFMA B-fragment order, f16 hi + residual*2048 lo.
// Frag (et,kc): lane holds B[k=kc*32+(lane>>4)*8+j][e=et*16+(lane&15)], j=0..7.
// Packed addr: ((et*128 + kc)*64 + lane)*8.  Also zeroes flag_cnt.
// ---------------------------------------------------------------------------
__global__ __launch_bounds__(256) void wsplit(const float* __restrict__ W,
                                              _Float16* __restrict__ Whp,
                                              _Float16* __restrict__ Wlp,
                                              int* __restrict__ flag_cnt) {
    int fi = blockIdx.x * 256 + threadIdx.x;        // 0 .. 16*128*64-1
    if (fi == 0) *flag_cnt = 0;
    int lane = fi & 63;
    int kc = (fi >> 6) & 127;
    int et = fi >> 13;
    int e = et * 16 + (lane & 15);
    int k = kc * 32 + ((lane >> 4) << 3);
    const float* src = W + (size_t)e * DIM + k;
    float4 a = *(const float4*)src;
    float4 b = *(const float4*)(src + 4);
    float f[8] = {a.x, a.y, a.z, a.w, b.x, b.y, b.z, b.w};
    H8 hh, hl;
#pragma unroll
    for (int j = 0; j < 8; j++) {
        float ws = f[j] * 256.0f;                   // exact (pow2)
        _Float16 h = (_Float16)ws;                  // RNE
        float r = ws - (float)h;                    // exact residual
        hh.v[j] = h;
        hl.v[j] = (_Float16)(r * 2048.0f);
    }
    *(int4*)(Whp + (size_t)fi * 8) = hh.q;
    *(int4*)(Wlp + (size_t)fi * 8) = hl.q;
}

// ---------------------------------------------------------------------------
// Kernel 1: partial logits = x @ W^T (k-chunked), 3-term f16-split MFMA.
// Block: 256 thr = 4 waves; tile m=64 (shared), n=128 (wave n=32, 2 et each).
// Grid (128 m, 2 n, 3 k-chunks) = 768 blocks = 3/CU, 12 waves/CU.
// A: f32 coalesced -> regs -> convert once -> padded LDS (dbuf). B: packed
// frags, coalesced dwordx4, reg double-buffered. Barrier = lgkmcnt-only
// s_barrier: global prefetches survive the barrier (no vmcnt(0) drain).
// ---------------------------------------------------------------------------
__global__ __launch_bounds__(256, 3) void score_gemm(const float* __restrict__ x,
                                                     const _Float16* __restrict__ Whp,
                                                     const _Float16* __restrict__ Wlp,
                                                     float* __restrict__ parts) {
    __shared__ __align__(16) _Float16 sAh[2][64 * PITCH];
    __shared__ __align__(16) _Float16 sAl[2][64 * PITCH];

    const int m0 = blockIdx.x * 64;
    const int nb = blockIdx.y;
    const int chunk = blockIdx.z;
    const int kcb = 43 * chunk;
    const int kce = kcb + (chunk == 2 ? 42 : 43);

    const int tid = threadIdx.x;
    const int lane = tid & 63;
    const int wave = tid >> 6;
    const int et0 = nb * 8 + wave * 2;              // two 16-expert tiles per wave

    // A staging: thread owns row srow, 8 consecutive k-floats at scol
    const int srow = tid >> 2;
    const int scol = (tid & 3) * 8;
    const int sidx = srow * PITCH + scol;
    const float* xrow = x + (size_t)(m0 + srow) * DIM + scol;

    f4 accH[4][2], accC[4][2];
#pragma unroll
    for (int i = 0; i < 4; i++)
#pragma unroll
        for (int j = 0; j < 2; j++) { accH[i][j] = (f4)0.0f; accC[i][j] = (f4)0.0f; }

    float4 ra[2][2];
    half8 bh[2][2], bl[2][2];

#define LOADRAW(S, KC)                                                         \
    {                                                                          \
        const float* p_ = xrow + (size_t)(KC) * 32;                            \
        ra[S][0] = *(const float4*)p_;                                         \
        ra[S][1] = *(const float4*)(p_ + 4);                                   \
    }

#define CONV(S, B_)                                                            \
    {                                                                          \
        float f_[8] = {ra[S][0].x, ra[S][0].y, ra[S][0].z, ra[S][0].w,         \
                       ra[S][1].x, ra[S][1].y, ra[S][1].z, ra[S][1].w};        \
        H8 hh_, hl_;                                                           \
        _Pragma("unroll") for (int j_ = 0; j_ < 8; j_++) {                     \
            float xv_ = f_[j_] * 16.0f;                                        \
            _Float16 hv_ = (_Float16)xv_;                                      \
            float r_ = xv_ - (float)hv_;                                       \
            hh_.v[j_] = hv_;                                                   \
            hl_.v[j_] = (_Float16)(r_ * 2048.0f);                              \
        }                                                                      \
        *(int4*)&sAh[B_][sidx] = hh_.q;                                        \
        *(int4*)&sAl[B_][sidx] = hl_.q;                                        \
    }

#define BLOAD(P_, KC)                                                          \
    _Pragma("unroll") for (int nt_ = 0; nt_ < 2; nt_++) {                      \
        size_t o_ = ((size_t)((et0 + nt_) * 128 + (KC)) * 64 + lane) * 8;      \
        bh[P_][nt_] = *(const half8*)(Whp + o_);                               \
        bl[P_][nt_] = *(const half8*)(Wlp + o_);                               \
    }

#define MFMA_PHASE(P)                                                          \
    _Pragma("unroll") for (int mt_ = 0; mt_ < 4; mt_++) {                      \
        int ra_ = (mt_ * 16 + (lane & 15)) * PITCH + ((lane >> 4) << 3);       \
        half8 ah_ = *(const half8*)&sAh[P][ra_];                               \
        half8 al_ = *(const half8*)&sAl[P][ra_];                               \
        _Pragma("unroll") for (int nt_ = 0; nt_ < 2; nt_++) {                  \
            accH[mt_][nt_] = __builtin_amdgcn_mfma_f32_16x16x32_f16(           \
                ah_, bh[P][nt_], accH[mt_][nt_], 0, 0, 0);                     \
            accC[mt_][nt_] = __builtin_amdgcn_mfma_f32_16x16x32_f16(           \
                ah_, bl[P][nt_], accC[mt_][nt_], 0, 0, 0);                     \
            accC[mt_][nt_] = __builtin_amdgcn_mfma_f32_16x16x32_f16(           \
                al_, bh[P][nt_], accC[mt_][nt_], 0, 0, 0);                     \
        }                                                                      \
    }

// LDS-writes-only barrier: does NOT drain vmcnt, so global prefetches stay in
// flight across it (the m97 vmcnt(0)-drain was the 75% stall in rounds 4/5).
#define BARRIER() asm volatile("s_waitcnt lgkmcnt(0)\n\ts_barrier" ::: "memory")

#define ITER(KC, P)                                                            \
    {                                                                          \
        if ((KC) + 1 < kce) { BLOAD(P ^ 1, (KC) + 1) }                         \
        if ((KC) + 2 < kce) { LOADRAW(P, (KC) + 2) }                           \
        MFMA_PHASE(P)                                                          \
        if ((KC) + 1 < kce) { CONV(P ^ 1, P ^ 1) }                             \
        BARRIER();                                                             \
    }

    // prologue: A(kcb)->buf0; raw A(kcb+1) staged; B(kcb) in regs parity 0
    LOADRAW(0, kcb)
    CONV(0, 0)
    LOADRAW(1, kcb + 1)
    BLOAD(0, kcb)
    BARRIER();

    int kc = kcb;
    while (kc + 2 <= kce) {
        ITER(kc, 0)
        ITER(kc + 1, 1)
        kc += 2;
    }
    if (kc < kce) { ITER(kc, 0) }

    // epilogue: partial = accH + accC/2048 (final /4096 applied in route).
    // C layout: col=lane&15, row=(lane>>4)*4+r.
    float* pc = parts + (size_t)chunk * TOKENS * NEXP;
#pragma unroll
    for (int mt = 0; mt < 4; mt++)
#pragma unroll
        for (int nt = 0; nt < 2; nt++) {
            int m = m0 + mt * 16 + ((lane >> 4) << 2);
            int e = (et0 + nt) * 16 + (lane & 15);
#pragma unroll
            for (int r = 0; r < 4; r++)
                pc[(size_t)(m + r) * NEXP + e] =
                    accH[mt][nt][r] + accC[mt][nt][r] * (1.0f / 2048.0f);
        }
#undef LOADRAW
#undef CONV
#undef BLOAD
#undef MFMA_PHASE
#undef BARRIER
#undef ITER
}

// ---------------------------------------------------------------------------
// Kernel 2: sum partials -> logits -> sigmoid -> routing + constant-threshold
// margin flagging. 4 tokens / 256-thr block, 1 wave per token.
// ---------------------------------------------------------------------------
__global__ __launch_bounds__(256) void route_kernel(const float* __restrict__ parts,
                                                    const float* __restrict__ bias,
                                                    float* __restrict__ out_w,
                                                    float* __restrict__ out_i,
                                                    int* __restrict__ flag_cnt,
                                                    int* __restrict__ flag_list) {
    const int t = blockIdx.x * 4 + (threadIdx.x >> 6);
    const int l = threadIdx.x & 63;

    const float* p = parts + (size_t)t * NEXP + (l << 2);
    float4 q0 = *(const float4*)p;
    float4 q1 = *(const float4*)(p + (size_t)TOKENS * NEXP);
    float4 q2 = *(const float4*)(p + (size_t)2 * TOKENS * NEXP);
    float4 b4 = *(const float4*)&bias[l << 2];
    float sc[4], sb[4];
    {
        float lg0 = (q0.x + q1.x + q2.x) * (1.0f / 4096.0f);
        float lg1 = (q0.y + q1.y + q2.y) * (1.0f / 4096.0f);
        float lg2 = (q0.z + q1.z + q2.z) * (1.0f / 4096.0f);
        float lg3 = (q0.w + q1.w + q2.w) * (1.0f / 4096.0f);
        sc[0] = 1.0f / (1.0f + expf(-lg0));
        sc[1] = 1.0f / (1.0f + expf(-lg1));
        sc[2] = 1.0f / (1.0f + expf(-lg2));
        sc[3] = 1.0f / (1.0f + expf(-lg3));
        sb[0] = sc[0] + b4.x; sb[1] = sc[1] + b4.y;
        sb[2] = sc[2] + b4.z; sb[3] = sc[3] + b4.w;
    }

    // per-lane top-3 of its 4 biased scores
    float v1 = sb[0], v2 = -1e30f, v3 = -1e30f;
#pragma unroll
    for (int c = 1; c < 4; c++) {
        float xv = sb[c];
        if (xv > v1) { v3 = v2; v2 = v1; v1 = xv; }
        else if (xv > v2) { v3 = v2; v2 = xv; }
        else if (xv > v3) { v3 = xv; }
    }

    // butterfly top-3 merge across the 8 lanes of the group
#pragma unroll
    for (int m = 1; m < 8; m <<= 1) {
        float o1 = __shfl_xor(v1, m, 64);
        float o2 = __shfl_xor(v2, m, 64);
        float o3 = __shfl_xor(v3, m, 64);
        bool aw = (v1 >= o1);
        float A1 = aw ? v1 : o1, A2 = aw ? v2 : o2, A3 = aw ? v3 : o3;
        float B1 = aw ? o1 : v1, B2 = aw ? o2 : v2;
        float n2, n3;
        if (A2 >= B1) { n2 = A2; n3 = fmaxf(B1, A3); }
        else          { n2 = B1; n3 = fmaxf(A2, B2); }
        v1 = A1; v2 = n2; v3 = n3;
    }
    float gscore = v1 + v2;
    float gap23 = v2 - v3;                  // within-group top2-vs-3 gap
#pragma unroll
    for (int m = 8; m < 64; m <<= 1) gap23 = fminf(gap23, __shfl_xor(gap23, m, 64));

    float gs[8];
#pragma unroll
    for (int g = 0; g < 8; g++) gs[g] = __shfl(gscore, g << 3, 64);

    const int mygrp = l >> 3;
    int rank = 0;
#pragma unroll
    for (int g = 0; g < 8; g++) {
        bool better = (gs[g] > gscore) || (gs[g] == gscore && g < mygrp);
        rank += (g != mygrp && better) ? 1 : 0;
    }
    const bool sel = rank < 4;

    // group 4th-vs-5th gap
    float minsel = 1e30f, maxuns = -1e30f;
#pragma unroll
    for (int g = 0; g < 8; g++) {
        int rg = 0;
#pragma unroll
        for (int g2 = 0; g2 < 8; g2++)
            rg += (g2 != g && ((gs[g2] > gs[g]) || (gs[g2] == gs[g] && g2 < g))) ? 1 : 0;
        if (rg < 4) minsel = fminf(minsel, gs[g]); else maxuns = fmaxf(maxuns, gs[g]);
    }
    float gap45 = minsel - maxuns;

    float cand[4];
#pragma unroll
    for (int c = 0; c < 4; c++) cand[c] = sel ? sb[c] : 0.0f;

    // serial top-9 extraction (9th only for the boundary gap)
    float wv[8], wi[8], vb[9];
    float wsum = 0.0f;
#pragma unroll
    for (int r = 0; r < 9; r++) {
        float v = cand[0];
        int idx = (l << 2);
#pragma unroll
        for (int c = 1; c < 4; c++) {
            if (cand[c] > v) { v = cand[c]; idx = (l << 2) + c; }
        }
#pragma unroll
        for (int m = 32; m >= 1; m >>= 1) {
            float ov = __shfl_xor(v, m, 64);
            int oi = __shfl_xor(idx, m, 64);
            if (ov > v || (ov == v && oi < idx)) { v = ov; idx = oi; }
        }
        vb[r] = v;
        if (r < 8) {
            const int cc = idx & 3;
            const bool own = (idx >> 2) == l;
            cand[0] = (own && cc == 0) ? -__builtin_inff() : cand[0];
            cand[1] = (own && cc == 1) ? -__builtin_inff() : cand[1];
            cand[2] = (own && cc == 2) ? -__builtin_inff() : cand[2];
            cand[3] = (own && cc == 3) ? -__builtin_inff() : cand[3];
            float tmp = (cc == 0) ? sc[0] : (cc == 1) ? sc[1] : (cc == 2) ? sc[2] : sc[3];
            float ws = __shfl(tmp, idx >> 2, 64);
            wv[r] = ws;
            wi[r] = (float)idx;
            wsum += ws;
        }
    }
    float mingap = 1e30f;
#pragma unroll
    for (int r = 0; r < 8; r++) mingap = fminf(mingap, vb[r] - vb[r + 1]);

    const float scale = ROUTE_SCALE / wsum;
    if (l == 0) {
        float* ow = out_w + (size_t)t * TK;
        float* oi = out_i + (size_t)t * TK;
#pragma unroll
        for (int r = 0; r < 8; r++) ow[r] = wv[r] * scale;
#pragma unroll
        for (int r = 0; r < 8; r++) oi[r] = wi[r];
        if (gap23 < TH1 || gap45 < TH2 || mingap < TH1) {
            int pos = atomicAdd(flag_cnt, 1);
            flag_list[pos] = t;
        }
    }
}

// ---------------------------------------------------------------------------
// Kernel 3: fixup — flagged tokens recomputed with the bit-identical serial
// fp32 fmaf chain + exact re-route.
// R3: R2's LDS ring was LDS-read-bound (SQ_LDS_BANK_CONFLICT 967k ~= the
// whole 110 µs; 4 MB/token through ds_read_b128 floors at ~40-50 µs even
// conflict-free). W is thread-private -- no sharing needed, so W goes back
// to plain global loads into a DEPTH-4 register ring (4 named slots x 8
// float4 = 128 VGPR, all indices static; R1's failure was depth 8 = 256 VGPR
// over the v255 cap -> scratch). Slot d's loads are issued 4 chunk-steps
// before use, so the compiler emits counted vmcnt waits and ~24-32 loads
// stay in flight per thread: T_chunk = max(chain ~150, lat/4 ~225) cyc.
// x stays in LDS (uniform-address broadcast b128 reads, conflict-free).
// fmaf chain order and operand values untouched -> bit-identical output.
// ---------------------------------------------------------------------------
__global__ __launch_bounds__(256, 1) void fixup_kernel(const float* __restrict__ x,
                                                       const float* __restrict__ W,
                                                       const float* __restrict__ bias,
                                                       const int* __restrict__ flag_cnt,
                                                       const int* __restrict__ flag_list,
                                                       float* __restrict__ out_w,
                                                       float* __restrict__ out_i) {
    __shared__ float S[NEXP];
    __shared__ __align__(16) float sx[DIM];           // 16 KB
    const int tid = threadIdx.x;

#define FILL(BUF, S_)                                                          \
    _Pragma("unroll") for (int q_ = 0; q_ < 8; q_++)                           \
        BUF[q_] = *(const float4*)(wr + (S_) * 32 + q_ * 4);

#define CONSUME(BUF, S_)                                                       \
    {                                                                          \
        const float* xb_ = sx + (S_) * 32;                                     \
        _Pragma("unroll") for (int q_ = 0; q_ < 8; q_++) {                     \
            const float4 wv = BUF[q_];                                         \
            const float4 xv = *(const float4*)(xb_ + q_ * 4);                  \
            acc = fmaf(xv.x, wv.x, acc);                                       \
            acc = fmaf(xv.y, wv.y, acc);                                       \
            acc = fmaf(xv.z, wv.z, acc);                                       \
            acc = fmaf(xv.w, wv.w, acc);                                       \
        }                                                                      \
    }

    const int n = *flag_cnt;
    for (int i = blockIdx.x; i < n; i += gridDim.x) {
        const int t = flag_list[i];
        const float* xr = x + (size_t)t * DIM;
        // cooperative, coalesced x-row stage: 4 float4 per thread
#pragma unroll
        for (int j = 0; j < 4; j++) {
            const int idx = (j * 256 + tid) * 4;
            *(float4*)&sx[idx] = *(const float4*)(xr + idx);
        }
        __syncthreads();

        const float* wr = W + (size_t)tid * DIM;
        float4 wb0[8], wb1[8], wb2[8], wb3[8];      // depth-4 ring, 128 VGPR
        FILL(wb0, 0)
        FILL(wb1, 1)
        FILL(wb2, 2)
        FILL(wb3, 3)

        float acc = 0.0f;
        for (int c4 = 0; c4 < 31; c4++) {           // chunks 4*c4 .. 4*c4+3
            const int s = c4 * 4;
            CONSUME(wb0, s)
            FILL(wb0, s + 4)
            CONSUME(wb1, s + 1)
            FILL(wb1, s + 5)
            CONSUME(wb2, s + 2)
            FILL(wb2, s + 6)
            CONSUME(wb3, s + 3)
            FILL(wb3, s + 7)
        }
        CONSUME(wb0, 124)
        CONSUME(wb1, 125)
        CONSUME(wb2, 126)
        CONSUME(wb3, 127)

        S[tid] = 1.0f / (1.0f + expf(-acc));
        __syncthreads();
        if (tid < 64) {
            const int l = tid;
            float sc[4] = {S[4 * l], S[4 * l + 1], S[4 * l + 2], S[4 * l + 3]};
            float4 b4 = *(const float4*)&bias[4 * l];
            float sb[4] = {sc[0] + b4.x, sc[1] + b4.y, sc[2] + b4.z, sc[3] + b4.w};

            float h1 = fmaxf(sb[0], sb[1]), q1 = fminf(sb[0], sb[1]);
            float h2 = fmaxf(sb[2], sb[3]), q2 = fminf(sb[2], sb[3]);
            float m1 = fmaxf(h1, h2);
            float m2 = fmaxf(fminf(h1, h2), fmaxf(q1, q2));
#pragma unroll
            for (int m = 1; m < 8; m <<= 1) {
                float o1 = __shfl_xor(m1, m, 64);
                float o2 = __shfl_xor(m2, m, 64);
                float nm1 = fmaxf(m1, o1);
                float nm2 = fmaxf(fminf(m1, o1), fmaxf(m2, o2));
                m1 = nm1; m2 = nm2;
            }
            float gscore = m1 + m2;
            float gs[8];
#pragma unroll
            for (int g = 0; g < 8; g++) gs[g] = __shfl(gscore, g << 3, 64);
            const int mygrp = l >> 3;
            int rank = 0;
#pragma unroll
            for (int g = 0; g < 8; g++) {
                bool better = (gs[g] > gscore) || (gs[g] == gscore && g < mygrp);
                rank += (g != mygrp && better) ? 1 : 0;
            }
            const bool selg = rank < 4;
            float cand[4];
#pragma unroll
            for (int c = 0; c < 4; c++) cand[c] = selg ? sb[c] : 0.0f;
            float wv[8], wi[8];
            float wsum = 0.0f;
#pragma unroll
            for (int r = 0; r < 8; r++) {
                float v = cand[0];
                int idx = (l << 2);
#pragma unroll
                for (int c = 1; c < 4; c++) {
                    if (cand[c] > v) { v = cand[c]; idx = (l << 2) + c; }
                }
#pragma unroll
                for (int m = 32; m >= 1; m >>= 1) {
                    float ov = __shfl_xor(v, m, 64);
                    int oi = __shfl_xor(idx, m, 64);
                    if (ov > v || (ov == v && oi < idx)) { v = ov; idx = oi; }
                }
                const int cc = idx & 3;
                const bool own = (idx >> 2) == l;
                cand[0] = (own && cc == 0) ? -__builtin_inff() : cand[0];
                cand[1] = (own && cc == 1) ? -__builtin_inff() : cand[1];
                cand[2] = (own && cc == 2) ? -__builtin_inff() : cand[2];
                cand[3] = (own && cc == 3) ? -__builtin_inff() : cand[3];
                float tmp = (cc == 0) ? sc[0] : (cc == 1) ? sc[1] : (cc == 2) ? sc[2] : sc[3];
                float ws = __shfl(tmp, idx >> 2, 64);
                wv[r] = ws;
                wi[r] = (float)idx;
                wsum += ws;
            }
            const float scale = ROUTE_SCALE / wsum;
            if (l == 0) {
                float* ow = out_w + (size_t)t * TK;
                float* oi = out_i + (size_t)t * TK;
#pragma unroll
                for (int r = 0; r < 8; r++) ow[r] = wv[r] * scale;
#pragma unroll
                for (int r = 0; r < 8; r++) oi[r] = wi[r];
            }
        }
        __syncthreads();
    }
#undef FILL
#undef CONSUME
}

extern "C" void kernel_launch(void* const* d_in, const int* in_sizes, int n_in,
                              void* d_out, int out_size, void* d_ws, size_t ws_size,
                              hipStream_t stream) {
    const float* x = (const float*)d_in[0];
    const float* W = (const float*)d_in[1];
    const float* bias = (const float*)d_in[2];
    float* out = (float*)d_out;

    char* ws = (char*)d_ws;
    float* parts = (float*)ws;                                        // 3 x 8 MB
    _Float16* Whp = (_Float16*)(ws + (size_t)3 * TOKENS * NEXP * 4);  // 2 MB
    _Float16* Wlp = Whp + (size_t)NEXP * DIM;                         // 2 MB
    int* flag_cnt = (int*)((char*)(Wlp + (size_t)NEXP * DIM));
    int* flag_list = flag_cnt + 4;                                    // up to 8192 ints

    wsplit<<<512, 256, 0, stream>>>(W, Whp, Wlp, flag_cnt);

    dim3 gGemm(TOKENS / 64, 2, 3);   // 768 blocks = 3/CU
    score_gemm<<<gGemm, 256, 0, stream>>>(x, Whp, Wlp, parts);

    route_kernel<<<TOKENS / 4, 256, 0, stream>>>(parts, bias, out,
                                                 out + (size_t)TOKENS * TK,
                                                 flag_cnt, flag_list);
    fixup_kernel<<<256, 256, 0, stream>>>(x, W, bias, flag_cnt, flag_list,
                                          out, out + (size_t)TOKENS * TK);
}

// Round 4
// 301.575 us; speedup vs baseline: 1.2104x; 1.2104x over previous
//
#include <hip/hip_runtime.h>
#include <math.h>

#define TOKENS 8192
#define DIM 4096
#define NEXP 256
#define TK 8
#define ROUTE_SCALE 2.5f
#define TH1 1e-5f   // score-gap trust threshold (~20x worst-case f16-split score error)
#define TH2 2e-5f   // group-score (sum of 2) gap threshold

#define PITCH 40    // halves per LDS row: 80 B = 5*16 -> b128-aligned every row, odd stride banks

typedef _Float16 half8 __attribute__((ext_vector_type(8)));
typedef float f4 __attribute__((ext_vector_type(4)));
union H8 { half8 v; int4 q; };

// ---------------------------------------------------------------------------
// Pre-kernel: pack W*256 into MFMA B-fragment order, f16 hi + residual*2048 lo,
// AND write a transposed raw-f32 copy Wt4[kq][e] = W[e][4kq..4kq+3] for the
// fixup kernel (coalesced per-expert reads there). Also zeroes flag_cnt.
// ---------------------------------------------------------------------------
__global__ __launch_bounds__(256) void wsplit(const float* __restrict__ W,
                                              _Float16* __restrict__ Whp,
                                              _Float16* __restrict__ Wlp,
                                              float4* __restrict__ Wt4,
                                              int* __restrict__ flag_cnt) {
    int fi = blockIdx.x * 256 + threadIdx.x;        // 0 .. 16*128*64-1
    if (fi == 0) *flag_cnt = 0;
    int lane = fi & 63;
    int kc = (fi >> 6) & 127;
    int et = fi >> 13;
    int e = et * 16 + (lane & 15);
    int k = kc * 32 + ((lane >> 4) << 3);
    const float* src = W + (size_t)e * DIM + k;
    float4 a = *(const float4*)src;
    float4 b = *(const float4*)(src + 4);
    // transpose copy (raw f32 words -> fixup chain stays bit-identical)
    int kq = kc * 8 + ((lane >> 4) << 1);
    Wt4[(size_t)kq * NEXP + e] = a;
    Wt4[(size_t)(kq + 1) * NEXP + e] = b;
    float f[8] = {a.x, a.y, a.z, a.w, b.x, b.y, b.z, b.w};
    H8 hh, hl;
#pragma unroll
    for (int j = 0; j < 8; j++) {
        float ws = f[j] * 256.0f;                   // exact (pow2)
        _Float16 h = (_Float16)ws;                  // RNE
        float r = ws - (float)h;                    // exact residual
        hh.v[j] = h;
        hl.v[j] = (_Float16)(r * 2048.0f);
    }
    *(int4*)(Whp + (size_t)fi * 8) = hh.q;
    *(int4*)(Wlp + (size_t)fi * 8) = hl.q;
}

// ---------------------------------------------------------------------------
// Kernel 1: partial logits = x @ W^T (k-chunked), 3-term f16-split MFMA.
// Block: 256 thr = 4 waves; tile m=64 (shared), n=128 (wave n=32, 2 et each).
// Grid (128 m, 2 n, 3 k-chunks) = 768 blocks = 3/CU, 12 waves/CU.
// A: f32 coalesced -> regs -> convert once -> padded LDS (dbuf). B: packed
// frags, coalesced dwordx4, reg double-buffered. Barrier = lgkmcnt-only
// s_barrier: global prefetches survive the barrier (no vmcnt(0) drain).
// ---------------------------------------------------------------------------
__global__ __launch_bounds__(256, 3) void score_gemm(const float* __restrict__ x,
                                                     const _Float16* __restrict__ Whp,
                                                     const _Float16* __restrict__ Wlp,
                                                     float* __restrict__ parts) {
    __shared__ __align__(16) _Float16 sAh[2][64 * PITCH];
    __shared__ __align__(16) _Float16 sAl[2][64 * PITCH];

    const int m0 = blockIdx.x * 64;
    const int nb = blockIdx.y;
    const int chunk = blockIdx.z;
    const int kcb = 43 * chunk;
    const int kce = kcb + (chunk == 2 ? 42 : 43);

    const int tid = threadIdx.x;
    const int lane = tid & 63;
    const int wave = tid >> 6;
    const int et0 = nb * 8 + wave * 2;              // two 16-expert tiles per wave

    // A staging: thread owns row srow, 8 consecutive k-floats at scol
    const int srow = tid >> 2;
    const int scol = (tid & 3) * 8;
    const int sidx = srow * PITCH + scol;
    const float* xrow = x + (size_t)(m0 + srow) * DIM + scol;

    f4 accH[4][2], accC[4][2];
#pragma unroll
    for (int i = 0; i < 4; i++)
#pragma unroll
        for (int j = 0; j < 2; j++) { accH[i][j] = (f4)0.0f; accC[i][j] = (f4)0.0f; }

    float4 ra[2][2];
    half8 bh[2][2], bl[2][2];

#define LOADRAW(S, KC)                                                         \
    {                                                                          \
        const float* p_ = xrow + (size_t)(KC) * 32;                            \
        ra[S][0] = *(const float4*)p_;                                         \
        ra[S][1] = *(const float4*)(p_ + 4);                                   \
    }

#define CONV(S, B_)                                                            \
    {                                                                          \
        float f_[8] = {ra[S][0].x, ra[S][0].y, ra[S][0].z, ra[S][0].w,         \
                       ra[S][1].x, ra[S][1].y, ra[S][1].z, ra[S][1].w};        \
        H8 hh_, hl_;                                                           \
        _Pragma("unroll") for (int j_ = 0; j_ < 8; j_++) {                     \
            float xv_ = f_[j_] * 16.0f;                                        \
            _Float16 hv_ = (_Float16)xv_;                                      \
            float r_ = xv_ - (float)hv_;                                       \
            hh_.v[j_] = hv_;                                                   \
            hl_.v[j_] = (_Float16)(r_ * 2048.0f);                              \
        }                                                                      \
        *(int4*)&sAh[B_][sidx] = hh_.q;                                        \
        *(int4*)&sAl[B_][sidx] = hl_.q;                                        \
    }

#define BLOAD(P_, KC)                                                          \
    _Pragma("unroll") for (int nt_ = 0; nt_ < 2; nt_++) {                      \
        size_t o_ = ((size_t)((et0 + nt_) * 128 + (KC)) * 64 + lane) * 8;      \
        bh[P_][nt_] = *(const half8*)(Whp + o_);                               \
        bl[P_][nt_] = *(const half8*)(Wlp + o_);                               \
    }

#define MFMA_PHASE(P)                                                          \
    _Pragma("unroll") for (int mt_ = 0; mt_ < 4; mt_++) {                      \
        int ra_ = (mt_ * 16 + (lane & 15)) * PITCH + ((lane >> 4) << 3);       \
        half8 ah_ = *(const half8*)&sAh[P][ra_];                               \
        half8 al_ = *(const half8*)&sAl[P][ra_];                               \
        _Pragma("unroll") for (int nt_ = 0; nt_ < 2; nt_++) {                  \
            accH[mt_][nt_] = __builtin_amdgcn_mfma_f32_16x16x32_f16(           \
                ah_, bh[P][nt_], accH[mt_][nt_], 0, 0, 0);                     \
            accC[mt_][nt_] = __builtin_amdgcn_mfma_f32_16x16x32_f16(           \
                ah_, bl[P][nt_], accC[mt_][nt_], 0, 0, 0);                     \
            accC[mt_][nt_] = __builtin_amdgcn_mfma_f32_16x16x32_f16(           \
                al_, bh[P][nt_], accC[mt_][nt_], 0, 0, 0);                     \
        }                                                                      \
    }

// LDS-writes-only barrier: does NOT drain vmcnt, so global prefetches stay in
// flight across it (the m97 vmcnt(0)-drain was the 75% stall in rounds 4/5).
#define BARRIER() asm volatile("s_waitcnt lgkmcnt(0)\n\ts_barrier" ::: "memory")

#define ITER(KC, P)                                                            \
    {                                                                          \
        if ((KC) + 1 < kce) { BLOAD(P ^ 1, (KC) + 1) }                         \
        if ((KC) + 2 < kce) { LOADRAW(P, (KC) + 2) }                           \
        MFMA_PHASE(P)                                                          \
        if ((KC) + 1 < kce) { CONV(P ^ 1, P ^ 1) }                             \
        BARRIER();                                                             \
    }

    // prologue: A(kcb)->buf0; raw A(kcb+1) staged; B(kcb) in regs parity 0
    LOADRAW(0, kcb)
    CONV(0, 0)
    LOADRAW(1, kcb + 1)
    BLOAD(0, kcb)
    BARRIER();

    int kc = kcb;
    while (kc + 2 <= kce) {
        ITER(kc, 0)
        ITER(kc + 1, 1)
        kc += 2;
    }
    if (kc < kce) { ITER(kc, 0) }

    // epilogue: partial = accH + accC/2048 (final /4096 applied in route).
    // C layout: col=lane&15, row=(lane>>4)*4+r.
    float* pc = parts + (size_t)chunk * TOKENS * NEXP;
#pragma unroll
    for (int mt = 0; mt < 4; mt++)
#pragma unroll
        for (int nt = 0; nt < 2; nt++) {
            int m = m0 + mt * 16 + ((lane >> 4) << 2);
            int e = (et0 + nt) * 16 + (lane & 15);
#pragma unroll
            for (int r = 0; r < 4; r++)
                pc[(size_t)(m + r) * NEXP + e] =
                    accH[mt][nt][r] + accC[mt][nt][r] * (1.0f / 2048.0f);
        }
#undef LOADRAW
#undef CONV
#undef BLOAD
#undef MFMA_PHASE
#undef BARRIER
#undef ITER
}

// ---------------------------------------------------------------------------
// Kernel 2: sum partials -> logits -> sigmoid -> routing + constant-threshold
// margin flagging. 4 tokens / 256-thr block, 1 wave per token.
// ---------------------------------------------------------------------------
__global__ __launch_bounds__(256) void route_kernel(const float* __restrict__ parts,
                                                    const float* __restrict__ bias,
                                                    float* __restrict__ out_w,
                                                    float* __restrict__ out_i,
                                                    int* __restrict__ flag_cnt,
                                                    int* __restrict__ flag_list) {
    const int t = blockIdx.x * 4 + (threadIdx.x >> 6);
    const int l = threadIdx.x & 63;

    const float* p = parts + (size_t)t * NEXP + (l << 2);
    float4 q0 = *(const float4*)p;
    float4 q1 = *(const float4*)(p + (size_t)TOKENS * NEXP);
    float4 q2 = *(const float4*)(p + (size_t)2 * TOKENS * NEXP);
    float4 b4 = *(const float4*)&bias[l << 2];
    float sc[4], sb[4];
    {
        float lg0 = (q0.x + q1.x + q2.x) * (1.0f / 4096.0f);
        float lg1 = (q0.y + q1.y + q2.y) * (1.0f / 4096.0f);
        float lg2 = (q0.z + q1.z + q2.z) * (1.0f / 4096.0f);
        float lg3 = (q0.w + q1.w + q2.w) * (1.0f / 4096.0f);
        sc[0] = 1.0f / (1.0f + expf(-lg0));
        sc[1] = 1.0f / (1.0f + expf(-lg1));
        sc[2] = 1.0f / (1.0f + expf(-lg2));
        sc[3] = 1.0f / (1.0f + expf(-lg3));
        sb[0] = sc[0] + b4.x; sb[1] = sc[1] + b4.y;
        sb[2] = sc[2] + b4.z; sb[3] = sc[3] + b4.w;
    }

    // per-lane top-3 of its 4 biased scores
    float v1 = sb[0], v2 = -1e30f, v3 = -1e30f;
#pragma unroll
    for (int c = 1; c < 4; c++) {
        float xv = sb[c];
        if (xv > v1) { v3 = v2; v2 = v1; v1 = xv; }
        else if (xv > v2) { v3 = v2; v2 = xv; }
        else if (xv > v3) { v3 = xv; }
    }

    // butterfly top-3 merge across the 8 lanes of the group
#pragma unroll
    for (int m = 1; m < 8; m <<= 1) {
        float o1 = __shfl_xor(v1, m, 64);
        float o2 = __shfl_xor(v2, m, 64);
        float o3 = __shfl_xor(v3, m, 64);
        bool aw = (v1 >= o1);
        float A1 = aw ? v1 : o1, A2 = aw ? v2 : o2, A3 = aw ? v3 : o3;
        float B1 = aw ? o1 : v1, B2 = aw ? o2 : v2;
        float n2, n3;
        if (A2 >= B1) { n2 = A2; n3 = fmaxf(B1, A3); }
        else          { n2 = B1; n3 = fmaxf(A2, B2); }
        v1 = A1; v2 = n2; v3 = n3;
    }
    float gscore = v1 + v2;
    float gap23 = v2 - v3;                  // within-group top2-vs-3 gap
#pragma unroll
    for (int m = 8; m < 64; m <<= 1) gap23 = fminf(gap23, __shfl_xor(gap23, m, 64));

    float gs[8];
#pragma unroll
    for (int g = 0; g < 8; g++) gs[g] = __shfl(gscore, g << 3, 64);

    const int mygrp = l >> 3;
    int rank = 0;
#pragma unroll
    for (int g = 0; g < 8; g++) {
        bool better = (gs[g] > gscore) || (gs[g] == gscore && g < mygrp);
        rank += (g != mygrp && better) ? 1 : 0;
    }
    const bool sel = rank < 4;

    // group 4th-vs-5th gap
    float minsel = 1e30f, maxuns = -1e30f;
#pragma unroll
    for (int g = 0; g < 8; g++) {
        int rg = 0;
#pragma unroll
        for (int g2 = 0; g2 < 8; g2++)
            rg += (g2 != g && ((gs[g2] > gs[g]) || (gs[g2] == gs[g] && g2 < g))) ? 1 : 0;
        if (rg < 4) minsel = fminf(minsel, gs[g]); else maxuns = fmaxf(maxuns, gs[g]);
    }
    float gap45 = minsel - maxuns;

    float cand[4];
#pragma unroll
    for (int c = 0; c < 4; c++) cand[c] = sel ? sb[c] : 0.0f;

    // serial top-9 extraction (9th only for the boundary gap)
    float wv[8], wi[8], vb[9];
    float wsum = 0.0f;
#pragma unroll
    for (int r = 0; r < 9; r++) {
        float v = cand[0];
        int idx = (l << 2);
#pragma unroll
        for (int c = 1; c < 4; c++) {
            if (cand[c] > v) { v = cand[c]; idx = (l << 2) + c; }
        }
#pragma unroll
        for (int m = 32; m >= 1; m >>= 1) {
            float ov = __shfl_xor(v, m, 64);
            int oi = __shfl_xor(idx, m, 64);
            if (ov > v || (ov == v && oi < idx)) { v = ov; idx = oi; }
        }
        vb[r] = v;
        if (r < 8) {
            const int cc = idx & 3;
            const bool own = (idx >> 2) == l;
            cand[0] = (own && cc == 0) ? -__builtin_inff() : cand[0];
            cand[1] = (own && cc == 1) ? -__builtin_inff() : cand[1];
            cand[2] = (own && cc == 2) ? -__builtin_inff() : cand[2];
            cand[3] = (own && cc == 3) ? -__builtin_inff() : cand[3];
            float tmp = (cc == 0) ? sc[0] : (cc == 1) ? sc[1] : (cc == 2) ? sc[2] : sc[3];
            float ws = __shfl(tmp, idx >> 2, 64);
            wv[r] = ws;
            wi[r] = (float)idx;
            wsum += ws;
        }
    }
    float mingap = 1e30f;
#pragma unroll
    for (int r = 0; r < 8; r++) mingap = fminf(mingap, vb[r] - vb[r + 1]);

    const float scale = ROUTE_SCALE / wsum;
    if (l == 0) {
        float* ow = out_w + (size_t)t * TK;
        float* oi = out_i + (size_t)t * TK;
#pragma unroll
        for (int r = 0; r < 8; r++) ow[r] = wv[r] * scale;
#pragma unroll
        for (int r = 0; r < 8; r++) oi[r] = wi[r];
        if (gap23 < TH1 || gap45 < TH2 || mingap < TH1) {
            int pos = atomicAdd(flag_cnt, 1);
            flag_list[pos] = t;
        }
    }
}

// ---------------------------------------------------------------------------
// Kernel 3: fixup — flagged tokens recomputed with the bit-identical serial
// fp32 fmaf chain + exact re-route.
// R4: all prior variants (serial / LDS ring / reg ring) sat at ~2250 cyc per
// 32 KB chunk, warm OR cold -> transaction-rate-bound: per-lane 16 KB-strided
// rows make every wave load touch 64 distinct lines (2048 transactions/chunk
// at ~1/cyc). Fix = COALESCE: read the transposed copy Wt4[kq][e] written by
// wsplit. Lanes = consecutive e -> 1 KB contiguous per instr = 8 transactions
// (8x fewer). Depth-4 static register ring (128 VGPR) covers residual
// latency; n blocks share one 4 MB Wt4 through L2/L3. Chain order and f32
// operand values are untouched -> bit-identical output.
// ---------------------------------------------------------------------------
__global__ __launch_bounds__(256, 1) void fixup_kernel(const float* __restrict__ x,
                                                       const float4* __restrict__ Wt4,
                                                       const float* __restrict__ bias,
                                                       const int* __restrict__ flag_cnt,
                                                       const int* __restrict__ flag_list,
                                                       float* __restrict__ out_w,
                                                       float* __restrict__ out_i) {
    __shared__ float S[NEXP];
    __shared__ __align__(16) float sx[DIM];           // 16 KB
    const int tid = threadIdx.x;

#define FILL(BUF, S_)                                                          \
    _Pragma("unroll") for (int q_ = 0; q_ < 8; q_++)                           \
        BUF[q_] = wt4r[(size_t)((S_) * 8 + q_) * NEXP];

#define CONSUME(BUF, S_)                                                       \
    {                                                                          \
        const float* xb_ = sx + (S_) * 32;                                     \
        _Pragma("unroll") for (int q_ = 0; q_ < 8; q_++) {                     \
            const float4 wv = BUF[q_];                                         \
            const float4 xv = *(const float4*)(xb_ + q_ * 4);                  \
            acc = fmaf(xv.x, wv.x, acc);                                       \
            acc = fmaf(xv.y, wv.y, acc);                                       \
            acc = fmaf(xv.z, wv.z, acc);                                       \
            acc = fmaf(xv.w, wv.w, acc);                                       \
        }                                                                      \
    }

    const int n = *flag_cnt;
    for (int i = blockIdx.x; i < n; i += gridDim.x) {
        const int t = flag_list[i];
        const float* xr = x + (size_t)t * DIM;
        // cooperative, coalesced x-row stage: 4 float4 per thread
#pragma unroll
        for (int j = 0; j < 4; j++) {
            const int idx = (j * 256 + tid) * 4;
            *(float4*)&sx[idx] = *(const float4*)(xr + idx);
        }
        __syncthreads();

        const float4* wt4r = Wt4 + tid;             // thread = expert column
        float4 wb0[8], wb1[8], wb2[8], wb3[8];      // depth-4 ring, 128 VGPR
        FILL(wb0, 0)
        FILL(wb1, 1)
        FILL(wb2, 2)
        FILL(wb3, 3)

        float acc = 0.0f;
        for (int c4 = 0; c4 < 31; c4++) {           // chunks 4*c4 .. 4*c4+3
            const int s = c4 * 4;
            CONSUME(wb0, s)
            FILL(wb0, s + 4)
            CONSUME(wb1, s + 1)
            FILL(wb1, s + 5)
            CONSUME(wb2, s + 2)
            FILL(wb2, s + 6)
            CONSUME(wb3, s + 3)
            FILL(wb3, s + 7)
        }
        CONSUME(wb0, 124)
        CONSUME(wb1, 125)
        CONSUME(wb2, 126)
        CONSUME(wb3, 127)

        S[tid] = 1.0f / (1.0f + expf(-acc));
        __syncthreads();
        if (tid < 64) {
            const int l = tid;
            float sc[4] = {S[4 * l], S[4 * l + 1], S[4 * l + 2], S[4 * l + 3]};
            float4 b4 = *(const float4*)&bias[4 * l];
            float sb[4] = {sc[0] + b4.x, sc[1] + b4.y, sc[2] + b4.z, sc[3] + b4.w};

            float h1 = fmaxf(sb[0], sb[1]), q1 = fminf(sb[0], sb[1]);
            float h2 = fmaxf(sb[2], sb[3]), q2 = fminf(sb[2], sb[3]);
            float m1 = fmaxf(h1, h2);
            float m2 = fmaxf(fminf(h1, h2), fmaxf(q1, q2));
#pragma unroll
            for (int m = 1; m < 8; m <<= 1) {
                float o1 = __shfl_xor(m1, m, 64);
                float o2 = __shfl_xor(m2, m, 64);
                float nm1 = fmaxf(m1, o1);
                float nm2 = fmaxf(fminf(m1, o1), fmaxf(m2, o2));
                m1 = nm1; m2 = nm2;
            }
            float gscore = m1 + m2;
            float gs[8];
#pragma unroll
            for (int g = 0; g < 8; g++) gs[g] = __shfl(gscore, g << 3, 64);
            const int mygrp = l >> 3;
            int rank = 0;
#pragma unroll
            for (int g = 0; g < 8; g++) {
                bool better = (gs[g] > gscore) || (gs[g] == gscore && g < mygrp);
                rank += (g != mygrp && better) ? 1 : 0;
            }
            const bool selg = rank < 4;
            float cand[4];
#pragma unroll
            for (int c = 0; c < 4; c++) cand[c] = selg ? sb[c] : 0.0f;
            float wv[8], wi[8];
            float wsum = 0.0f;
#pragma unroll
            for (int r = 0; r < 8; r++) {
                float v = cand[0];
                int idx = (l << 2);
#pragma unroll
                for (int c = 1; c < 4; c++) {
                    if (cand[c] > v) { v = cand[c]; idx = (l << 2) + c; }
                }
#pragma unroll
                for (int m = 32; m >= 1; m >>= 1) {
                    float ov = __shfl_xor(v, m, 64);
                    int oi = __shfl_xor(idx, m, 64);
                    if (ov > v || (ov == v && oi < idx)) { v = ov; idx = oi; }
                }
                const int cc = idx & 3;
                const bool own = (idx >> 2) == l;
                cand[0] = (own && cc == 0) ? -__builtin_inff() : cand[0];
                cand[1] = (own && cc == 1) ? -__builtin_inff() : cand[1];
                cand[2] = (own && cc == 2) ? -__builtin_inff() : cand[2];
                cand[3] = (own && cc == 3) ? -__builtin_inff() : cand[3];
                float tmp = (cc == 0) ? sc[0] : (cc == 1) ? sc[1] : (cc == 2) ? sc[2] : sc[3];
                float ws = __shfl(tmp, idx >> 2, 64);
                wv[r] = ws;
                wi[r] = (float)idx;
                wsum += ws;
            }
            const float scale = ROUTE_SCALE / wsum;
            if (l == 0) {
                float* ow = out_w + (size_t)t * TK;
                float* oi = out_i + (size_t)t * TK;
#pragma unroll
                for (int r = 0; r < 8; r++) ow[r] = wv[r] * scale;
#pragma unroll
                for (int r = 0; r < 8; r++) oi[r] = wi[r];
            }
        }
        __syncthreads();
    }
#undef FILL
#undef CONSUME
}

extern "C" void kernel_launch(void* const* d_in, const int* in_sizes, int n_in,
                              void* d_out, int out_size, void* d_ws, size_t ws_size,
                              hipStream_t stream) {
    const float* x = (const float*)d_in[0];
    const float* W = (const float*)d_in[1];
    const float* bias = (const float*)d_in[2];
    float* out = (float*)d_out;

    char* p = (char*)d_ws;
    float* parts = (float*)p;            p += (size_t)3 * TOKENS * NEXP * 4;  // 24 MB
    _Float16* Whp = (_Float16*)p;        p += (size_t)NEXP * DIM * 2;         // 2 MB
    _Float16* Wlp = (_Float16*)p;        p += (size_t)NEXP * DIM * 2;         // 2 MB
    int* flag_cnt = (int*)p;
    int* flag_list = flag_cnt + 4;       p += 40960;                          // flags
    float4* Wt4 = (float4*)p;                                                 // 4 MB

    wsplit<<<512, 256, 0, stream>>>(W, Whp, Wlp, Wt4, flag_cnt);

    dim3 gGemm(TOKENS / 64, 2, 3);   // 768 blocks = 3/CU
    score_gemm<<<gGemm, 256, 0, stream>>>(x, Whp, Wlp, parts);

    route_kernel<<<TOKENS / 4, 256, 0, stream>>>(parts, bias, out,
                                                 out + (size_t)TOKENS * TK,
                                                 flag_cnt, flag_list);
    fixup_kernel<<<256, 256, 0, stream>>>(x, Wt4, bias, flag_cnt, flag_list,
                                          out, out + (size_t)TOKENS * TK);
}